// Round 16
// baseline (374.619 us; speedup 1.0000x reference)
//
#include <hip/hip_runtime.h>
#include <stdint.h>

#define DIMS 256
#define NT 4096
#define NROWS 65536
#define THETA 1.5e-4f

typedef float    f32x4_t __attribute__((ext_vector_type(4)));
typedef _Float16 f16x8_t __attribute__((ext_vector_type(8)));
typedef _Float16 f16x4_t __attribute__((ext_vector_type(4)));

#define GLDS16(gsrc, ldst) \
  __builtin_amdgcn_global_load_lds((const __attribute__((address_space(1))) void*)(gsrc), \
      (__attribute__((address_space(3))) void*)(ldst), 16, 0, 0)

// ---- kernel 0: fused se (bit-exact numpy pairwise) + cb16 = fp16(cb*512) ----
__global__ __launch_bounds__(64) void vq_prep(const float* __restrict__ cb,
                                              float* __restrict__ se,
                                              _Float16* __restrict__ cb16){
  __shared__ float sq[256];
  const int k = blockIdx.x;
  const int tid = threadIdx.x;
  float4 v = *(const float4*)(cb + (size_t)k*256 + tid*4);
  f16x4_t p;
  p.x = (_Float16)(v.x * 512.f);
  p.y = (_Float16)(v.y * 512.f);
  p.z = (_Float16)(v.z * 512.f);
  p.w = (_Float16)(v.w * 512.f);
  *(f16x4_t*)(cb16 + (size_t)k*256 + tid*4) = p;
  sq[tid*4+0] = __fmul_rn(v.x, v.x);
  sq[tid*4+1] = __fmul_rn(v.y, v.y);
  sq[tid*4+2] = __fmul_rn(v.z, v.z);
  sq[tid*4+3] = __fmul_rn(v.w, v.w);
  __syncthreads();
  if (tid < 16){
    const int h = tid >> 3, j = tid & 7;
    float r = sq[h*128 + j];
    #pragma unroll
    for (int i = 1; i < 16; ++i) r = __fadd_rn(r, sq[h*128 + j + 8*i]);
    r = __fadd_rn(r, __shfl_xor(r, 1));
    r = __fadd_rn(r, __shfl_xor(r, 2));
    r = __fadd_rn(r, __shfl_xor(r, 4));
    r = __fadd_rn(r, __shfl_xor(r, 8));
    if (tid == 0) se[k] = r;
  }
}

// ================= kernel 1: scores (glds B, swizzled LDS) + TOP-3 tracking =================
#define AH(r,c)    Ah[(size_t)(r)*264 + (c)]
#define QQ(t,c)    q[(size_t)(t)*260 + (c)]

// top-3 insert: values v1<=v2<=v3, indices for 1,2 only. strict < keeps lower index on tie
// (exact ties -> margin 0 -> flagged -> exact refine resolves).
#define T3I(v, i, V1, I1, V2, I2, V3) { \
  bool lt1 = (v) < (V1), lt2 = (v) < (V2), lt3 = (v) < (V3); \
  (V3) = lt2 ? (V2) : (lt3 ? (v) : (V3)); \
  (V2) = lt1 ? (V1) : (lt2 ? (v) : (V2)); \
  (I2) = lt1 ? (I1) : (lt2 ? (i) : (I2)); \
  (V1) = lt1 ? (v) : (V1); \
  (I1) = lt1 ? (i) : (I1); }

#define DECL_T3(M,R) \
  float b1_##M##R = 3.4e38f, b2_##M##R = 3.4e38f, b3_##M##R = 3.4e38f; \
  int bi_##M##R = 0x7fffffff, bj_##M##R = 0x7fffffff;

#define FOLD(M,R) { \
  float v; \
  v = fmaf(a##M##0[R], NEGI, ec0); T3I(v, kb +  0, b1_##M##R, bi_##M##R, b2_##M##R, bj_##M##R, b3_##M##R); \
  v = fmaf(a##M##1[R], NEGI, ec1); T3I(v, kb + 16, b1_##M##R, bi_##M##R, b2_##M##R, bj_##M##R, b3_##M##R); \
  v = fmaf(a##M##2[R], NEGI, ec2); T3I(v, kb + 32, b1_##M##R, bi_##M##R, b2_##M##R, bj_##M##R, b3_##M##R); \
  v = fmaf(a##M##3[R], NEGI, ec3); T3I(v, kb + 48, b1_##M##R, bi_##M##R, b2_##M##R, bj_##M##R, b3_##M##R); }

// merge two sorted top-3 sets (mine) <- (other): standard 3-smallest-of-union
#define M3BODY(ov1, oi1, ov2, oi2, ov3) { \
  bool t_ = (ov1) < v1; \
  float m1_ = t_ ? (ov1) : v1;  int j1_ = t_ ? (oi1) : i1; \
  float xb_ = t_ ? v1 : (ov1);  int jb_ = t_ ? i1 : (oi1); \
  float a2_ = t_ ? (ov2) : v2;  int ja_ = t_ ? (oi2) : i2; \
  float a3_ = t_ ? (ov3) : v3; \
  float bb2_ = t_ ? v2 : (ov2); \
  bool u_ = a2_ < xb_; \
  float m2_ = u_ ? a2_ : xb_; int j2_ = u_ ? ja_ : jb_; \
  float m3_ = u_ ? fminf(a3_, xb_) : fminf(a2_, bb2_); \
  v1 = m1_; i1 = j1_; v2 = m2_; i2 = j2_; v3 = m3_; }

#define MSTEP3(MK) { \
  float ov1 = __shfl_xor(v1, MK), ov2 = __shfl_xor(v2, MK), ov3 = __shfl_xor(v3, MK); \
  int oi1 = __shfl_xor(i1, MK), oi2 = __shfl_xor(i2, MK); \
  M3BODY(ov1, oi1, ov2, oi2, ov3) }

#define MERGE(M,R) { \
  float v1 = b1_##M##R, v2 = b2_##M##R, v3 = b3_##M##R; \
  int i1 = bi_##M##R, i2 = bj_##M##R; \
  MSTEP3(1) MSTEP3(2) MSTEP3(4) MSTEP3(8) \
  if (fr == 0){ \
    comb4[(wr32 + (M)*16 + fq*4 + (R))*4 + wc] = make_float4(v1, __int_as_float(i1), v2, __int_as_float(i2)); \
    comb3[(wr32 + (M)*16 + fq*4 + (R))*4 + wc] = v3; } }

__global__ __launch_bounds__(512, 1) void vq_scores(
    const float* __restrict__ x, const float* __restrict__ cb,
    const _Float16* __restrict__ cb16, const float* __restrict__ se,
    float* __restrict__ out0, float* __restrict__ out2,
    unsigned* __restrict__ wlB, uint4* __restrict__ wlA,
    unsigned* __restrict__ cntB, unsigned* __restrict__ cntA,
    double* __restrict__ accd)
{
  // smem: Ah [64][264] f16 @0 (33792); Bh 2x16384 @33792; comb4 @66560 (4096);
  // comb3 @70656 (1024); codeL @71680 (256); sxa @71936 (256). q f32 aliases Ah+Bh.
  __shared__ __align__(16) char smem[72192];
  _Float16* Ah   = (_Float16*)smem;
  char*     BhRaw= smem + 33792;
  float4*   comb4= (float4*)(smem + 66560);
  float*    comb3= (float*)(smem + 70656);
  int*      codeL= (int*)(smem + 71680);
  float*    sxa  = (float*)(smem + 71936);
  float*    q    = (float*)smem;

  const int tid  = threadIdx.x;
  const int lane = tid & 63;
  const int wid  = tid >> 6;
  const int wr   = wid >> 2;
  const int wc   = wid & 3;
  const int fr   = lane & 15;
  const int fq   = lane >> 4;
  const int wr32 = wr * 32;
  const int fq8  = fq * 8;
  const int wcfr = wc*64 + fr;
  const int n0   = blockIdx.x * 64;
  const int bb   = n0 >> 12;
  const int t0   = n0 & 4095;
  const float NEGI = -1.0f/256.0f;

  // per-lane glds source offsets (inverse swizzle on global src; LDS dest linear)
  const int cA = wid*32 + (lane >> 2);
  const int cB = cA + 16;
  const int qA = (lane & 3) ^ ((cA >> 1) & 3);
  const int qB = (lane & 3) ^ ((cB >> 1) & 3);
  const char* cbB = (const char*)cb16;
  const size_t srcA = (size_t)cA*512 + qA*16;
  const size_t srcB = (size_t)cB*512 + qB*16;
  char* dstA = BhRaw + wid*2048;          // HW adds lane*16
  char* dstB = dstA + 1024;

  int bOff[4];
  #pragma unroll
  for (int cf = 0; cf < 4; ++cf){
    const int cd = wc*64 + cf*16 + fr;
    bOff[cf] = cd*64 + ((fq ^ ((cd >> 1) & 3)) << 4);
  }

  GLDS16(cbB + srcA, dstA);
  GLDS16(cbB + srcB, dstB);

  // ---- stage A once: 64 rows x 256 c, fp16; NT loads ----
  {
    const int dup = tid >> 7;
    const int c4  = tid & 7;
    const int tt  = ((tid >> 3) & 15) << 2;
    #pragma unroll
    for (int cc2 = 0; cc2 < 2; ++cc2){
      const int c0 = (dup*2 + cc2) * 32;
      const float* xp = x + ((size_t)(bb*DIMS + c0 + c4*4))*NT + t0 + tt;
      f32x4_t va0 = __builtin_nontemporal_load((const f32x4_t*)(xp));
      f32x4_t va1 = __builtin_nontemporal_load((const f32x4_t*)(xp + NT));
      f32x4_t va2 = __builtin_nontemporal_load((const f32x4_t*)(xp + 2*NT));
      f32x4_t va3 = __builtin_nontemporal_load((const f32x4_t*)(xp + 3*NT));
      #pragma unroll
      for (int j = 0; j < 4; ++j){
        f16x4_t p;
        p.x = (_Float16)(va0[j]);
        p.y = (_Float16)(va1[j]);
        p.z = (_Float16)(va2[j]);
        p.w = (_Float16)(va3[j]);
        *(f16x4_t*)&AH(tt + j, c0 + c4*4) = p;
      }
    }
  }

  const f32x4_t Z = {0.f, 0.f, 0.f, 0.f};
  f32x4_t a00=Z,a01=Z,a02=Z,a03=Z, a10=Z,a11=Z,a12=Z,a13=Z;
  DECL_T3(0,0) DECL_T3(0,1) DECL_T3(0,2) DECL_T3(0,3)
  DECL_T3(1,0) DECL_T3(1,1) DECL_T3(1,2) DECL_T3(1,3)

  __syncthreads();   // full drain: A-tile visible, prologue glds landed

  for (int p = 0; p < 32; ++p){
    if (p){
      asm volatile("s_waitcnt vmcnt(0)" ::: "memory");
      __builtin_amdgcn_s_barrier();
      asm volatile("" ::: "memory");
    }
    const int nn = p + 1;
    if (nn < 32){
      const char* g = cbB + (size_t)(nn >> 3)*131072 + (size_t)(nn & 7)*64;
      char* d = (nn & 1) ? (dstA + 16384) : dstA;
      GLDS16(g + srcA, d);
      GLDS16(g + srcB, d + 1024);
    }
    {
      const char* bbuf = BhRaw + ((p & 1) << 14);
      f16x8_t bh0 = *(const f16x8_t*)(bbuf + bOff[0]);
      f16x8_t bh1 = *(const f16x8_t*)(bbuf + bOff[1]);
      f16x8_t bh2 = *(const f16x8_t*)(bbuf + bOff[2]);
      f16x8_t bh3 = *(const f16x8_t*)(bbuf + bOff[3]);
      const int cc = p & 7;
      f16x8_t ah0 = *(const f16x8_t*)&AH(wr32 + fr, cc*32 + fq8);
      f16x8_t ah1 = *(const f16x8_t*)&AH(wr32 + 16 + fr, cc*32 + fq8);
      __builtin_amdgcn_s_setprio(1);
      a00 = __builtin_amdgcn_mfma_f32_16x16x32_f16(ah0, bh0, a00, 0, 0, 0);
      a01 = __builtin_amdgcn_mfma_f32_16x16x32_f16(ah0, bh1, a01, 0, 0, 0);
      a02 = __builtin_amdgcn_mfma_f32_16x16x32_f16(ah0, bh2, a02, 0, 0, 0);
      a03 = __builtin_amdgcn_mfma_f32_16x16x32_f16(ah0, bh3, a03, 0, 0, 0);
      a10 = __builtin_amdgcn_mfma_f32_16x16x32_f16(ah1, bh0, a10, 0, 0, 0);
      a11 = __builtin_amdgcn_mfma_f32_16x16x32_f16(ah1, bh1, a11, 0, 0, 0);
      a12 = __builtin_amdgcn_mfma_f32_16x16x32_f16(ah1, bh2, a12, 0, 0, 0);
      a13 = __builtin_amdgcn_mfma_f32_16x16x32_f16(ah1, bh3, a13, 0, 0, 0);
      __builtin_amdgcn_s_setprio(0);
    }
    if ((p & 7) == 7){
      const int kb = (p >> 3)*256 + wcfr;
      const float ec0 = se[kb], ec1 = se[kb+16], ec2 = se[kb+32], ec3 = se[kb+48];
      FOLD(0,0) FOLD(0,1) FOLD(0,2) FOLD(0,3)
      FOLD(1,0) FOLD(1,1) FOLD(1,2) FOLD(1,3)
      a00=Z;a01=Z;a02=Z;a03=Z; a10=Z;a11=Z;a12=Z;a13=Z;
    }
  }

  MERGE(0,0) MERGE(0,1) MERGE(0,2) MERGE(0,3)
  MERGE(1,0) MERGE(1,1) MERGE(1,2) MERGE(1,3)
  __syncthreads();

  // approx row norms from staged fp16 A (fused loss; ~1e-4 accuracy is plenty)
  {
    const int row = tid >> 3, seg = tid & 7;
    float s = 0.f;
    #pragma unroll
    for (int k = 0; k < 4; ++k){
      f16x8_t hv = *(const f16x8_t*)&AH(row, seg*32 + k*8);
      #pragma unroll
      for (int e = 0; e < 8; ++e){
        float f = (float)hv[e];
        s = fmaf(f, f, s);
      }
    }
    s += __shfl_xor(s, 1);
    s += __shfl_xor(s, 2);
    s += __shfl_xor(s, 4);
    if (seg == 0) sxa[row] = s;
  }
  __syncthreads();

  if (tid < 64){
    float4 p4 = comb4[tid*4 + 0];
    float v1 = p4.x, v2 = p4.z, v3 = comb3[tid*4 + 0];
    int   i1 = __float_as_int(p4.y), i2 = __float_as_int(p4.w);
    #pragma unroll
    for (int w = 1; w < 4; ++w){
      float4 o4 = comb4[tid*4 + w];
      float ov3 = comb3[tid*4 + w];
      M3BODY(o4.x, __float_as_int(o4.y), o4.z, __float_as_int(o4.w), ov3)
    }
    const int r = n0 + tid;
    codeL[tid] = i1;
    out2[r] = (float)i1;
    bool f2 = !(v2 - v1 >= THETA);
    bool f3 = !(v3 - v1 >= THETA);
    if (f3){
      unsigned pos = atomicAdd(cntB, 1u);
      wlB[pos] = (unsigned)r;
    } else if (f2){
      unsigned pos = atomicAdd(cntA, 1u);
      wlA[pos] = make_uint4((unsigned)r, (unsigned)i1, (unsigned)i2, 0u);
    }
    double c = (f2 | f3) ? 0.0 : (double)(sxa[tid] + v1);
    #pragma unroll
    for (int m = 1; m < 64; m <<= 1) c += __shfl_xor(c, m);
    if (tid == 0) atomicAdd(accd, c);
  }
  __syncthreads();

  // ---- stage 64 selected fp32 codebook rows into q (aliases Ah/Bh) ----
  {
    const int r = tid >> 3, seg = tid & 7;
    const float* src = cb + (size_t)codeL[r] * DIMS;
    #pragma unroll
    for (int k = 0; k < 8; ++k){
      float4 v = *(const float4*)(src + k*32 + seg*4);
      *(float4*)&QQ(r, k*32 + seg*4) = v;
    }
  }
  __syncthreads();

  // ---- write out0 tile: channel-major, 64B-line coalesced; NT stores ----
  {
    #pragma unroll
    for (int jj = 0; jj < 2; ++jj){
      const int c = wid*32 + jj*16 + (lane >> 2);
      float* dst = out0 + ((size_t)(bb*256 + c))*NT + t0;
      #pragma unroll
      for (int ii = 0; ii < 4; ++ii){
        const int tl = ii*16 + (lane & 3)*4;
        f32x4_t v;
        v[0] = QQ(tl + 0, c);
        v[1] = QQ(tl + 1, c);
        v[2] = QQ(tl + 2, c);
        v[3] = QQ(tl + 3, c);
        __builtin_nontemporal_store(v, (f32x4_t*)(dst + tl));
      }
    }
  }
}

// ---- kernel 2a: pair-refine — bit-exact numpy compare of {i1,i2}, one thread/row ----
__global__ __launch_bounds__(256) void vq_pair(
    const float* __restrict__ x, const float* __restrict__ cb,
    const float* __restrict__ se,
    const uint4* __restrict__ wlA, const unsigned* __restrict__ cntA,
    float* __restrict__ out2, float* __restrict__ out0, double* __restrict__ accd)
{
  const unsigned n = *cntA;
  for (unsigned e = blockIdx.x*256 + threadIdx.x; e < n; e += gridDim.x*256){
    uint4 w = wlA[e];
    const int row = (int)w.x, i1 = (int)w.y, i2 = (int)w.z;
    const int b = row >> 12, t = row & 4095;
    const float* xp = x + (size_t)b*DIMS*NT + t;
    // pass 1: bit-exact sx (numpy pairwise: 16 accumulators, exact combine tree)
    float r[16];
    #pragma unroll
    for (int j = 0; j < 16; ++j) r[j] = 0.f;
    #pragma unroll
    for (int c = 0; c < 256; ++c){
      float xv = xp[(size_t)c * NT];
      r[((c >> 7) << 3) | (c & 7)] =
        __fadd_rn(r[((c >> 7) << 3) | (c & 7)], __fmul_rn(xv, xv));
    }
    float h0 = __fadd_rn(__fadd_rn(__fadd_rn(r[0],r[1]), __fadd_rn(r[2],r[3])),
                         __fadd_rn(__fadd_rn(r[4],r[5]), __fadd_rn(r[6],r[7])));
    float h1 = __fadd_rn(__fadd_rn(__fadd_rn(r[8],r[9]), __fadd_rn(r[10],r[11])),
                         __fadd_rn(__fadd_rn(r[12],r[13]), __fadd_rn(r[14],r[15])));
    float sx = __fadd_rn(h0, h1);
    // pass 2: two serial-fmaf dot chains (sgemm emulation), ascending c
    const float* c1 = cb + (size_t)i1 * DIMS;
    const float* c2 = cb + (size_t)i2 * DIMS;
    float m1 = 0.f, m2 = 0.f;
    #pragma unroll 8
    for (int c = 0; c < 256; ++c){
      float xv = xp[(size_t)c * NT];
      m1 = fmaf(xv, c1[c], m1);
      m2 = fmaf(xv, c2[c], m2);
    }
    float d1 = __fsub_rn(__fadd_rn(sx, se[i1]), __fadd_rn(m1, m1));
    float d2 = __fsub_rn(__fadd_rn(sx, se[i2]), __fadd_rn(m2, m2));
    int win; float dw;
    if (d1 < d2){ win = i1; dw = d1; }
    else if (d2 < d1){ win = i2; dw = d2; }
    else { win = (i1 < i2) ? i1 : i2; dw = d1; }
    out2[row] = (float)win;
    atomicAdd(accd, (double)dw);
    if (win != i1){
      const float* cw = cb + (size_t)win * DIMS;
      #pragma unroll 8
      for (int c = 0; c < 256; ++c)
        out0[((size_t)(b*DIMS + c))*NT + t] = cw[c];
    }
  }
}

// ---- kernel 2b: full exact rescan of rare 3-within-theta rows (8 rows/block) ----
__global__ __launch_bounds__(256) void vq_refine(
    const float* __restrict__ x, const float* __restrict__ cb,
    const float* __restrict__ se,
    const unsigned* __restrict__ wl, const unsigned* __restrict__ cnt,
    float* __restrict__ out2, float* __restrict__ out0, double* __restrict__ accd)
{
  __shared__ float eT[8][1024];
  __shared__ float xs[DIMS][8];
  __shared__ int   rows_s[8];
  __shared__ float sxs[8];
  __shared__ float wv[4][8];
  __shared__ int   wi[4][8];
  __shared__ int   wiF[8];

  const unsigned n = *cnt;
  const unsigned groups = (n + 7u) >> 3;
  const int tid  = threadIdx.x;
  const int lane = tid & 63;
  const int wid  = tid >> 6;

  for (unsigned g = blockIdx.x; g < groups; g += gridDim.x){
    __syncthreads();
    if (tid < 8){
      unsigned e = g*8u + (unsigned)tid;
      rows_s[tid] = (int)wl[e < n ? e : (n - 1u)];
    }
    __syncthreads();
    #pragma unroll
    for (int rep = 0; rep < 8; ++rep){
      int id = rep * 256 + tid;
      int c = id >> 3, r = id & 7;
      int row = rows_s[r];
      xs[c][r] = x[((size_t)((row >> 12)*DIMS + c))*NT + (row & 4095)];
    }
    __syncthreads();
    if (tid < 128){
      const int r = tid >> 4, hj = tid & 15;
      const int h = hj >> 3, j = hj & 7;
      float v0 = xs[h*128 + j][r];
      float s = __fmul_rn(v0, v0);
      #pragma unroll
      for (int i = 1; i < 16; ++i){
        float v = xs[h*128 + j + 8*i][r];
        s = __fadd_rn(s, __fmul_rn(v, v));
      }
      s = __fadd_rn(s, __shfl_xor(s, 1));
      s = __fadd_rn(s, __shfl_xor(s, 2));
      s = __fadd_rn(s, __shfl_xor(s, 4));
      s = __fadd_rn(s, __shfl_xor(s, 8));
      if (hj == 0) sxs[r] = s;
    }

    float s[8][4];
    #pragma unroll
    for (int r = 0; r < 8; ++r)
      #pragma unroll
      for (int u = 0; u < 4; ++u) s[r][u] = 0.f;

    for (int c0 = 0; c0 < DIMS; c0 += 8){
      __syncthreads();
      #pragma unroll
      for (int rep = 0; rep < 8; ++rep){
        int id2 = rep * 256 + tid;
        int k = id2 >> 1, qq = id2 & 1;
        float4 v = *(const float4*)&cb[(size_t)k * DIMS + c0 + qq * 4];
        eT[qq*4 + 0][k] = v.x; eT[qq*4 + 1][k] = v.y;
        eT[qq*4 + 2][k] = v.z; eT[qq*4 + 3][k] = v.w;
      }
      __syncthreads();
      #pragma unroll
      for (int cc = 0; cc < 8; ++cc){
        float4 ev = *(const float4*)&eT[cc][wid*256 + lane*4];
        #pragma unroll
        for (int r = 0; r < 8; ++r){
          float xv = xs[c0 + cc][r];
          s[r][0] = fmaf(xv, ev.x, s[r][0]);
          s[r][1] = fmaf(xv, ev.y, s[r][1]);
          s[r][2] = fmaf(xv, ev.z, s[r][2]);
          s[r][3] = fmaf(xv, ev.w, s[r][3]);
        }
      }
    }

    float4 sek = *(const float4*)&se[wid*256 + lane*4];
    #pragma unroll
    for (int r = 0; r < 8; ++r){
      const float sxv = sxs[r];
      float bv = 3.4e38f; int bi = 0x7fffffff;
      #pragma unroll
      for (int u = 0; u < 4; ++u){
        float d = __fsub_rn(__fadd_rn(sxv, (&sek.x)[u]),
                            __fadd_rn(s[r][u], s[r][u]));
        int k = wid*256 + lane*4 + u;
        if (d < bv || (d == bv && k < bi)) { bv = d; bi = k; }
      }
      #pragma unroll
      for (int m = 1; m < 64; m <<= 1){
        float ov = __shfl_xor(bv, m);
        int   oi = __shfl_xor(bi, m);
        if (ov < bv || (ov == bv && oi < bi)) { bv = ov; bi = oi; }
      }
      if (lane == 0){ wv[wid][r] = bv; wi[wid][r] = bi; }
    }
    __syncthreads();
    if (tid < 8){
      const int r = tid;
      float bv = wv[0][r]; int bi = wi[0][r];
      #pragma unroll
      for (int w = 1; w < 4; ++w){
        float ov = wv[w][r]; int oi = wi[w][r];
        if (ov < bv || (ov == bv && oi < bi)) { bv = ov; bi = oi; }
      }
      wiF[r] = bi;
      if (g*8u + (unsigned)r < n){
        int row = rows_s[r];
        out2[row] = (float)bi;
        atomicAdd(accd, (double)bv);
      }
    }
    __syncthreads();
    #pragma unroll
    for (int r = 0; r < 8; ++r){
      if (g*8u + (unsigned)r < n){
        int row  = rows_s[r];
        int code = wiF[r];
        out0[((size_t)((row >> 12)*256 + tid))*NT + (row & 4095)] = cb[(size_t)code*DIMS + tid];
      }
    }
  }
}

__global__ void vq_final(const double* __restrict__ accd, float* __restrict__ out1){
  *out1 = (float)(1.25 * (*accd) * (1.0 / 16777216.0));
}

extern "C" void kernel_launch(void* const* d_in, const int* in_sizes, int n_in,
                              void* d_out, int out_size, void* d_ws, size_t ws_size,
                              hipStream_t stream)
{
  const float* x  = (const float*)d_in[0];
  const float* cb = (const float*)d_in[1];
  float* out  = (float*)d_out;
  float* out0 = out;
  float* out1 = out + (size_t)16777216;   // vq_loss
  float* out2 = out + (size_t)16777217;   // indices as float [65536]

  char* ws = (char*)d_ws;
  double*   accd = (double*)(ws + 0);
  unsigned* cntA = (unsigned*)(ws + 8);
  unsigned* cntB = (unsigned*)(ws + 12);
  float*    se   = (float*)(ws + 64);        // 4 KiB
  unsigned* wlB  = (unsigned*)(ws + 4160);   // 64 KiB (16384 rows)
  uint4*    wlA  = (uint4*)(ws + 69696);     // 256 KiB (16384 entries)
  _Float16* cb16 = (_Float16*)(ws + 331840); // 512 KiB fp16 codebook (x512)

  hipMemsetAsync(d_ws, 0, 16, stream);       // zero accd + cntA + cntB
  vq_prep  <<<dim3(1024), dim3(64),  0, stream>>>(cb, se, cb16);
  vq_scores<<<dim3(1024), dim3(512), 0, stream>>>(x, cb, cb16, se, out0, out2,
                                                  wlB, wlA, cntB, cntA, accd);
  vq_pair  <<<dim3(32),   dim3(256), 0, stream>>>(x, cb, se, wlA, cntA, out2, out0, accd);
  vq_refine<<<dim3(64),   dim3(256), 0, stream>>>(x, cb, se, wlB, cntB, out2, out0, accd);
  vq_final <<<dim3(1),    dim3(1),   0, stream>>>(accd, out1);
}

// Round 17
// 179.584 us; speedup vs baseline: 2.0860x; 2.0860x over previous
//
#include <hip/hip_runtime.h>
#include <stdint.h>

#define DIMS 256
#define NT 4096
#define NROWS 65536
#define THETA 1.5e-4f

typedef float    f32x4_t __attribute__((ext_vector_type(4)));
typedef _Float16 f16x8_t __attribute__((ext_vector_type(8)));
typedef _Float16 f16x4_t __attribute__((ext_vector_type(4)));

#define GLDS16(gsrc, ldst) \
  __builtin_amdgcn_global_load_lds((const __attribute__((address_space(1))) void*)(gsrc), \
      (__attribute__((address_space(3))) void*)(ldst), 16, 0, 0)

// ---- kernel 0: fused se (bit-exact numpy pairwise) + cb16 = fp16(cb*512) ----
__global__ __launch_bounds__(64) void vq_prep(const float* __restrict__ cb,
                                              float* __restrict__ se,
                                              _Float16* __restrict__ cb16){
  __shared__ float sq[256];
  const int k = blockIdx.x;
  const int tid = threadIdx.x;
  float4 v = *(const float4*)(cb + (size_t)k*256 + tid*4);
  f16x4_t p;
  p.x = (_Float16)(v.x * 512.f);
  p.y = (_Float16)(v.y * 512.f);
  p.z = (_Float16)(v.z * 512.f);
  p.w = (_Float16)(v.w * 512.f);
  *(f16x4_t*)(cb16 + (size_t)k*256 + tid*4) = p;
  sq[tid*4+0] = __fmul_rn(v.x, v.x);
  sq[tid*4+1] = __fmul_rn(v.y, v.y);
  sq[tid*4+2] = __fmul_rn(v.z, v.z);
  sq[tid*4+3] = __fmul_rn(v.w, v.w);
  __syncthreads();
  if (tid < 16){
    const int h = tid >> 3, j = tid & 7;
    float r = sq[h*128 + j];
    #pragma unroll
    for (int i = 1; i < 16; ++i) r = __fadd_rn(r, sq[h*128 + j + 8*i]);
    r = __fadd_rn(r, __shfl_xor(r, 1));
    r = __fadd_rn(r, __shfl_xor(r, 2));
    r = __fadd_rn(r, __shfl_xor(r, 4));
    r = __fadd_rn(r, __shfl_xor(r, 8));
    if (tid == 0) se[k] = r;
  }
}

// ================= kernel 1: scores (glds B, swizzled LDS) + TOP-3 tracking =================
#define AH(r,c)    Ah[(size_t)(r)*264 + (c)]
#define QQ(t,c)    q[(size_t)(t)*260 + (c)]

#define T3I(v, i, V1, I1, V2, I2, V3) { \
  bool lt1 = (v) < (V1), lt2 = (v) < (V2), lt3 = (v) < (V3); \
  (V3) = lt2 ? (V2) : (lt3 ? (v) : (V3)); \
  (V2) = lt1 ? (V1) : (lt2 ? (v) : (V2)); \
  (I2) = lt1 ? (I1) : (lt2 ? (i) : (I2)); \
  (V1) = lt1 ? (v) : (V1); \
  (I1) = lt1 ? (i) : (I1); }

#define DECL_T3(M,R) \
  float b1_##M##R = 3.4e38f, b2_##M##R = 3.4e38f, b3_##M##R = 3.4e38f; \
  int bi_##M##R = 0x7fffffff, bj_##M##R = 0x7fffffff;

#define FOLD(M,R) { \
  float v; \
  v = fmaf(a##M##0[R], NEGI, ec0); T3I(v, kb +  0, b1_##M##R, bi_##M##R, b2_##M##R, bj_##M##R, b3_##M##R); \
  v = fmaf(a##M##1[R], NEGI, ec1); T3I(v, kb + 16, b1_##M##R, bi_##M##R, b2_##M##R, bj_##M##R, b3_##M##R); \
  v = fmaf(a##M##2[R], NEGI, ec2); T3I(v, kb + 32, b1_##M##R, bi_##M##R, b2_##M##R, bj_##M##R, b3_##M##R); \
  v = fmaf(a##M##3[R], NEGI, ec3); T3I(v, kb + 48, b1_##M##R, bi_##M##R, b2_##M##R, bj_##M##R, b3_##M##R); }

#define M3BODY(ov1, oi1, ov2, oi2, ov3) { \
  bool t_ = (ov1) < v1; \
  float m1_ = t_ ? (ov1) : v1;  int j1_ = t_ ? (oi1) : i1; \
  float xb_ = t_ ? v1 : (ov1);  int jb_ = t_ ? i1 : (oi1); \
  float a2_ = t_ ? (ov2) : v2;  int ja_ = t_ ? (oi2) : i2; \
  float a3_ = t_ ? (ov3) : v3; \
  float bb2_ = t_ ? v2 : (ov2); \
  bool u_ = a2_ < xb_; \
  float m2_ = u_ ? a2_ : xb_; int j2_ = u_ ? ja_ : jb_; \
  float m3_ = u_ ? fminf(a3_, xb_) : fminf(a2_, bb2_); \
  v1 = m1_; i1 = j1_; v2 = m2_; i2 = j2_; v3 = m3_; }

#define MSTEP3(MK) { \
  float ov1 = __shfl_xor(v1, MK), ov2 = __shfl_xor(v2, MK), ov3 = __shfl_xor(v3, MK); \
  int oi1 = __shfl_xor(i1, MK), oi2 = __shfl_xor(i2, MK); \
  M3BODY(ov1, oi1, ov2, oi2, ov3) }

#define MERGE(M,R) { \
  float v1 = b1_##M##R, v2 = b2_##M##R, v3 = b3_##M##R; \
  int i1 = bi_##M##R, i2 = bj_##M##R; \
  MSTEP3(1) MSTEP3(2) MSTEP3(4) MSTEP3(8) \
  if (fr == 0){ \
    comb4[(wr32 + (M)*16 + fq*4 + (R))*4 + wc] = make_float4(v1, __int_as_float(i1), v2, __int_as_float(i2)); \
    comb3[(wr32 + (M)*16 + fq*4 + (R))*4 + wc] = v3; } }

__global__ __launch_bounds__(512, 1) void vq_scores(
    const float* __restrict__ x, const float* __restrict__ cb,
    const _Float16* __restrict__ cb16, const float* __restrict__ se,
    float* __restrict__ out0, float* __restrict__ out2,
    unsigned* __restrict__ wlB, uint4* __restrict__ wlA,
    unsigned* __restrict__ cntB, unsigned* __restrict__ cntA,
    double* __restrict__ accd)
{
  __shared__ __align__(16) char smem[72192];
  _Float16* Ah   = (_Float16*)smem;
  char*     BhRaw= smem + 33792;
  float4*   comb4= (float4*)(smem + 66560);
  float*    comb3= (float*)(smem + 70656);
  int*      codeL= (int*)(smem + 71680);
  float*    sxa  = (float*)(smem + 71936);
  float*    q    = (float*)smem;

  const int tid  = threadIdx.x;
  const int lane = tid & 63;
  const int wid  = tid >> 6;
  const int wr   = wid >> 2;
  const int wc   = wid & 3;
  const int fr   = lane & 15;
  const int fq   = lane >> 4;
  const int wr32 = wr * 32;
  const int fq8  = fq * 8;
  const int wcfr = wc*64 + fr;
  const int n0   = blockIdx.x * 64;
  const int bb   = n0 >> 12;
  const int t0   = n0 & 4095;
  const float NEGI = -1.0f/256.0f;

  const int cA = wid*32 + (lane >> 2);
  const int cB = cA + 16;
  const int qA = (lane & 3) ^ ((cA >> 1) & 3);
  const int qB = (lane & 3) ^ ((cB >> 1) & 3);
  const char* cbB = (const char*)cb16;
  const size_t srcA = (size_t)cA*512 + qA*16;
  const size_t srcB = (size_t)cB*512 + qB*16;
  char* dstA = BhRaw + wid*2048;          // HW adds lane*16
  char* dstB = dstA + 1024;

  int bOff[4];
  #pragma unroll
  for (int cf = 0; cf < 4; ++cf){
    const int cd = wc*64 + cf*16 + fr;
    bOff[cf] = cd*64 + ((fq ^ ((cd >> 1) & 3)) << 4);
  }

  GLDS16(cbB + srcA, dstA);
  GLDS16(cbB + srcB, dstB);

  {
    const int dup = tid >> 7;
    const int c4  = tid & 7;
    const int tt  = ((tid >> 3) & 15) << 2;
    #pragma unroll
    for (int cc2 = 0; cc2 < 2; ++cc2){
      const int c0 = (dup*2 + cc2) * 32;
      const float* xp = x + ((size_t)(bb*DIMS + c0 + c4*4))*NT + t0 + tt;
      f32x4_t va0 = __builtin_nontemporal_load((const f32x4_t*)(xp));
      f32x4_t va1 = __builtin_nontemporal_load((const f32x4_t*)(xp + NT));
      f32x4_t va2 = __builtin_nontemporal_load((const f32x4_t*)(xp + 2*NT));
      f32x4_t va3 = __builtin_nontemporal_load((const f32x4_t*)(xp + 3*NT));
      #pragma unroll
      for (int j = 0; j < 4; ++j){
        f16x4_t p;
        p.x = (_Float16)(va0[j]);
        p.y = (_Float16)(va1[j]);
        p.z = (_Float16)(va2[j]);
        p.w = (_Float16)(va3[j]);
        *(f16x4_t*)&AH(tt + j, c0 + c4*4) = p;
      }
    }
  }

  const f32x4_t Z = {0.f, 0.f, 0.f, 0.f};
  f32x4_t a00=Z,a01=Z,a02=Z,a03=Z, a10=Z,a11=Z,a12=Z,a13=Z;
  DECL_T3(0,0) DECL_T3(0,1) DECL_T3(0,2) DECL_T3(0,3)
  DECL_T3(1,0) DECL_T3(1,1) DECL_T3(1,2) DECL_T3(1,3)

  __syncthreads();   // full drain: A-tile visible, prologue glds landed

  for (int p = 0; p < 32; ++p){
    if (p){
      asm volatile("s_waitcnt vmcnt(0)" ::: "memory");
      __builtin_amdgcn_s_barrier();
      asm volatile("" ::: "memory");
    }
    const int nn = p + 1;
    if (nn < 32){
      const char* g = cbB + (size_t)(nn >> 3)*131072 + (size_t)(nn & 7)*64;
      char* d = (nn & 1) ? (dstA + 16384) : dstA;
      GLDS16(g + srcA, d);
      GLDS16(g + srcB, d + 1024);
    }
    {
      const char* bbuf = BhRaw + ((p & 1) << 14);
      f16x8_t bh0 = *(const f16x8_t*)(bbuf + bOff[0]);
      f16x8_t bh1 = *(const f16x8_t*)(bbuf + bOff[1]);
      f16x8_t bh2 = *(const f16x8_t*)(bbuf + bOff[2]);
      f16x8_t bh3 = *(const f16x8_t*)(bbuf + bOff[3]);
      const int cc = p & 7;
      f16x8_t ah0 = *(const f16x8_t*)&AH(wr32 + fr, cc*32 + fq8);
      f16x8_t ah1 = *(const f16x8_t*)&AH(wr32 + 16 + fr, cc*32 + fq8);
      __builtin_amdgcn_s_setprio(1);
      a00 = __builtin_amdgcn_mfma_f32_16x16x32_f16(ah0, bh0, a00, 0, 0, 0);
      a01 = __builtin_amdgcn_mfma_f32_16x16x32_f16(ah0, bh1, a01, 0, 0, 0);
      a02 = __builtin_amdgcn_mfma_f32_16x16x32_f16(ah0, bh2, a02, 0, 0, 0);
      a03 = __builtin_amdgcn_mfma_f32_16x16x32_f16(ah0, bh3, a03, 0, 0, 0);
      a10 = __builtin_amdgcn_mfma_f32_16x16x32_f16(ah1, bh0, a10, 0, 0, 0);
      a11 = __builtin_amdgcn_mfma_f32_16x16x32_f16(ah1, bh1, a11, 0, 0, 0);
      a12 = __builtin_amdgcn_mfma_f32_16x16x32_f16(ah1, bh2, a12, 0, 0, 0);
      a13 = __builtin_amdgcn_mfma_f32_16x16x32_f16(ah1, bh3, a13, 0, 0, 0);
      __builtin_amdgcn_s_setprio(0);
    }
    if ((p & 7) == 7){
      const int kb = (p >> 3)*256 + wcfr;
      const float ec0 = se[kb], ec1 = se[kb+16], ec2 = se[kb+32], ec3 = se[kb+48];
      FOLD(0,0) FOLD(0,1) FOLD(0,2) FOLD(0,3)
      FOLD(1,0) FOLD(1,1) FOLD(1,2) FOLD(1,3)
      a00=Z;a01=Z;a02=Z;a03=Z; a10=Z;a11=Z;a12=Z;a13=Z;
    }
  }

  MERGE(0,0) MERGE(0,1) MERGE(0,2) MERGE(0,3)
  MERGE(1,0) MERGE(1,1) MERGE(1,2) MERGE(1,3)
  __syncthreads();

  {
    const int row = tid >> 3, seg = tid & 7;
    float s = 0.f;
    #pragma unroll
    for (int k = 0; k < 4; ++k){
      f16x8_t hv = *(const f16x8_t*)&AH(row, seg*32 + k*8);
      #pragma unroll
      for (int e = 0; e < 8; ++e){
        float f = (float)hv[e];
        s = fmaf(f, f, s);
      }
    }
    s += __shfl_xor(s, 1);
    s += __shfl_xor(s, 2);
    s += __shfl_xor(s, 4);
    if (seg == 0) sxa[row] = s;
  }
  __syncthreads();

  if (tid < 64){
    float4 p4 = comb4[tid*4 + 0];
    float v1 = p4.x, v2 = p4.z, v3 = comb3[tid*4 + 0];
    int   i1 = __float_as_int(p4.y), i2 = __float_as_int(p4.w);
    #pragma unroll
    for (int w = 1; w < 4; ++w){
      float4 o4 = comb4[tid*4 + w];
      float ov3 = comb3[tid*4 + w];
      M3BODY(o4.x, __float_as_int(o4.y), o4.z, __float_as_int(o4.w), ov3)
    }
    const int r = n0 + tid;
    codeL[tid] = i1;
    out2[r] = (float)i1;
    bool f2 = !(v2 - v1 >= THETA);
    bool f3 = !(v3 - v1 >= THETA);
    if (f3){
      unsigned pos = atomicAdd(cntB, 1u);
      wlB[pos] = (unsigned)r;
    } else if (f2){
      unsigned pos = atomicAdd(cntA, 1u);
      wlA[pos] = make_uint4((unsigned)r, (unsigned)i1, (unsigned)i2, 0u);
    }
    double c = (f2 | f3) ? 0.0 : (double)(sxa[tid] + v1);
    #pragma unroll
    for (int m = 1; m < 64; m <<= 1) c += __shfl_xor(c, m);
    if (tid == 0) atomicAdd(accd, c);
  }
  __syncthreads();

  {
    const int r = tid >> 3, seg = tid & 7;
    const float* src = cb + (size_t)codeL[r] * DIMS;
    #pragma unroll
    for (int k = 0; k < 8; ++k){
      float4 v = *(const float4*)(src + k*32 + seg*4);
      *(float4*)&QQ(r, k*32 + seg*4) = v;
    }
  }
  __syncthreads();

  {
    #pragma unroll
    for (int jj = 0; jj < 2; ++jj){
      const int c = wid*32 + jj*16 + (lane >> 2);
      float* dst = out0 + ((size_t)(bb*256 + c))*NT + t0;
      #pragma unroll
      for (int ii = 0; ii < 4; ++ii){
        const int tl = ii*16 + (lane & 3)*4;
        f32x4_t v;
        v[0] = QQ(tl + 0, c);
        v[1] = QQ(tl + 1, c);
        v[2] = QQ(tl + 2, c);
        v[3] = QQ(tl + 3, c);
        __builtin_nontemporal_store(v, (f32x4_t*)(dst + tl));
      }
    }
  }
}

// ---- kernel 2a: pair-refine, 32 rows/block, LDS-staged, bit-exact numpy compare ----
__global__ __launch_bounds__(256) void vq_pair(
    const float* __restrict__ x, const float* __restrict__ cb,
    const float* __restrict__ se,
    const uint4* __restrict__ wlA, const unsigned* __restrict__ cntA,
    float* __restrict__ out2, float* __restrict__ out0, double* __restrict__ accd)
{
  __shared__ float xs[256][33];   // 33792 B, padded: conflict-free both phases
  __shared__ uint4 wrow[32];
  __shared__ int   winS[32];

  const unsigned n = *cntA;
  const unsigned groups = (n + 31u) >> 5;
  const int tid = threadIdx.x;

  for (unsigned g = blockIdx.x; g < groups; g += gridDim.x){
    __syncthreads();   // protect xs/wrow/winS reuse across groups
    if (tid < 32){
      unsigned e = g*32u + (unsigned)tid;
      wrow[tid] = wlA[e < n ? e : (n - 1u)];
    }
    __syncthreads();
    // stage 32 rows of x: thread -> (r = tid&31, c = (tid>>5) + 8*rep)
    #pragma unroll
    for (int rep = 0; rep < 32; ++rep){
      const int r = tid & 31;
      const int c = (tid >> 5) + 8*rep;
      const int row = (int)wrow[r].x;
      xs[c][r] = x[((size_t)((row >> 12)*DIMS + c))*NT + (row & 4095)];
    }
    __syncthreads();

    if (tid < 32){
      const uint4 w = wrow[tid];
      const int row = (int)w.x, i1 = (int)w.y, i2 = (int)w.z;
      const float* c1 = cb + (size_t)i1 * DIMS;
      const float* c2 = cb + (size_t)i2 * DIMS;
      // single pass: bit-exact pairwise sx accumulators + two serial fmaf dot chains
      float racc[16];
      #pragma unroll
      for (int j = 0; j < 16; ++j) racc[j] = 0.f;
      float m1 = 0.f, m2 = 0.f;
      #pragma unroll
      for (int c = 0; c < 256; ++c){
        float xv = xs[c][tid];
        const int j = ((c >> 7) << 3) | (c & 7);
        racc[j] = __fadd_rn(racc[j], __fmul_rn(xv, xv));
        m1 = fmaf(xv, c1[c], m1);
        m2 = fmaf(xv, c2[c], m2);
      }
      float h0 = __fadd_rn(__fadd_rn(__fadd_rn(racc[0],racc[1]), __fadd_rn(racc[2],racc[3])),
                           __fadd_rn(__fadd_rn(racc[4],racc[5]), __fadd_rn(racc[6],racc[7])));
      float h1 = __fadd_rn(__fadd_rn(__fadd_rn(racc[8],racc[9]), __fadd_rn(racc[10],racc[11])),
                           __fadd_rn(__fadd_rn(racc[12],racc[13]), __fadd_rn(racc[14],racc[15])));
      float sx = __fadd_rn(h0, h1);
      float d1 = __fsub_rn(__fadd_rn(sx, se[i1]), __fadd_rn(m1, m1));
      float d2 = __fsub_rn(__fadd_rn(sx, se[i2]), __fadd_rn(m2, m2));
      int win; float dw;
      if (d1 < d2){ win = i1; dw = d1; }
      else if (d2 < d1){ win = i2; dw = d2; }
      else { win = (i1 < i2) ? i1 : i2; dw = d1; }
      const bool live = (g*32u + (unsigned)tid) < n;
      winS[tid] = (live && win != i1) ? win : -1;
      if (live){
        out2[row] = (float)win;
        atomicAdd(accd, (double)dw);
      }
    }
    __syncthreads();
    // block-parallel out0 patch for changed rows
    #pragma unroll
    for (int r = 0; r < 32; ++r){
      const int win = winS[r];
      if (win >= 0){
        const int row = (int)wrow[r].x;
        out0[((size_t)((row >> 12)*DIMS + tid))*NT + (row & 4095)] = cb[(size_t)win*DIMS + tid];
      }
    }
  }
}

// ---- kernel 2b: full exact rescan of rare 3-within-theta rows (8 rows/block) ----
__global__ __launch_bounds__(256) void vq_refine(
    const float* __restrict__ x, const float* __restrict__ cb,
    const float* __restrict__ se,
    const unsigned* __restrict__ wl, const unsigned* __restrict__ cnt,
    float* __restrict__ out2, float* __restrict__ out0, double* __restrict__ accd)
{
  __shared__ float eT[8][1024];
  __shared__ float xs[DIMS][8];
  __shared__ int   rows_s[8];
  __shared__ float sxs[8];
  __shared__ float wv[4][8];
  __shared__ int   wi[4][8];
  __shared__ int   wiF[8];

  const unsigned n = *cnt;
  const unsigned groups = (n + 7u) >> 3;
  const int tid  = threadIdx.x;
  const int lane = tid & 63;
  const int wid  = tid >> 6;

  for (unsigned g = blockIdx.x; g < groups; g += gridDim.x){
    __syncthreads();
    if (tid < 8){
      unsigned e = g*8u + (unsigned)tid;
      rows_s[tid] = (int)wl[e < n ? e : (n - 1u)];
    }
    __syncthreads();
    #pragma unroll
    for (int rep = 0; rep < 8; ++rep){
      int id = rep * 256 + tid;
      int c = id >> 3, r = id & 7;
      int row = rows_s[r];
      xs[c][r] = x[((size_t)((row >> 12)*DIMS + c))*NT + (row & 4095)];
    }
    __syncthreads();
    if (tid < 128){
      const int r = tid >> 4, hj = tid & 15;
      const int h = hj >> 3, j = hj & 7;
      float v0 = xs[h*128 + j][r];
      float s = __fmul_rn(v0, v0);
      #pragma unroll
      for (int i = 1; i < 16; ++i){
        float v = xs[h*128 + j + 8*i][r];
        s = __fadd_rn(s, __fmul_rn(v, v));
      }
      s = __fadd_rn(s, __shfl_xor(s, 1));
      s = __fadd_rn(s, __shfl_xor(s, 2));
      s = __fadd_rn(s, __shfl_xor(s, 4));
      s = __fadd_rn(s, __shfl_xor(s, 8));
      if (hj == 0) sxs[r] = s;
    }

    float s[8][4];
    #pragma unroll
    for (int r = 0; r < 8; ++r)
      #pragma unroll
      for (int u = 0; u < 4; ++u) s[r][u] = 0.f;

    for (int c0 = 0; c0 < DIMS; c0 += 8){
      __syncthreads();
      #pragma unroll
      for (int rep = 0; rep < 8; ++rep){
        int id2 = rep * 256 + tid;
        int k = id2 >> 1, qq = id2 & 1;
        float4 v = *(const float4*)&cb[(size_t)k * DIMS + c0 + qq * 4];
        eT[qq*4 + 0][k] = v.x; eT[qq*4 + 1][k] = v.y;
        eT[qq*4 + 2][k] = v.z; eT[qq*4 + 3][k] = v.w;
      }
      __syncthreads();
      #pragma unroll
      for (int cc = 0; cc < 8; ++cc){
        float4 ev = *(const float4*)&eT[cc][wid*256 + lane*4];
        #pragma unroll
        for (int r = 0; r < 8; ++r){
          float xv = xs[c0 + cc][r];
          s[r][0] = fmaf(xv, ev.x, s[r][0]);
          s[r][1] = fmaf(xv, ev.y, s[r][1]);
          s[r][2] = fmaf(xv, ev.z, s[r][2]);
          s[r][3] = fmaf(xv, ev.w, s[r][3]);
        }
      }
    }

    float4 sek = *(const float4*)&se[wid*256 + lane*4];
    #pragma unroll
    for (int r = 0; r < 8; ++r){
      const float sxv = sxs[r];
      float bv = 3.4e38f; int bi = 0x7fffffff;
      #pragma unroll
      for (int u = 0; u < 4; ++u){
        float d = __fsub_rn(__fadd_rn(sxv, (&sek.x)[u]),
                            __fadd_rn(s[r][u], s[r][u]));
        int k = wid*256 + lane*4 + u;
        if (d < bv || (d == bv && k < bi)) { bv = d; bi = k; }
      }
      #pragma unroll
      for (int m = 1; m < 64; m <<= 1){
        float ov = __shfl_xor(bv, m);
        int   oi = __shfl_xor(bi, m);
        if (ov < bv || (ov == bv && oi < bi)) { bv = ov; bi = oi; }
      }
      if (lane == 0){ wv[wid][r] = bv; wi[wid][r] = bi; }
    }
    __syncthreads();
    if (tid < 8){
      const int r = tid;
      float bv = wv[0][r]; int bi = wi[0][r];
      #pragma unroll
      for (int w = 1; w < 4; ++w){
        float ov = wv[w][r]; int oi = wi[w][r];
        if (ov < bv || (ov == bv && oi < bi)) { bv = ov; bi = oi; }
      }
      wiF[r] = bi;
      if (g*8u + (unsigned)r < n){
        int row = rows_s[r];
        out2[row] = (float)bi;
        atomicAdd(accd, (double)bv);
      }
    }
    __syncthreads();
    #pragma unroll
    for (int r = 0; r < 8; ++r){
      if (g*8u + (unsigned)r < n){
        int row  = rows_s[r];
        int code = wiF[r];
        out0[((size_t)((row >> 12)*256 + tid))*NT + (row & 4095)] = cb[(size_t)code*DIMS + tid];
      }
    }
  }
}

__global__ void vq_final(const double* __restrict__ accd, float* __restrict__ out1){
  *out1 = (float)(1.25 * (*accd) * (1.0 / 16777216.0));
}

extern "C" void kernel_launch(void* const* d_in, const int* in_sizes, int n_in,
                              void* d_out, int out_size, void* d_ws, size_t ws_size,
                              hipStream_t stream)
{
  const float* x  = (const float*)d_in[0];
  const float* cb = (const float*)d_in[1];
  float* out  = (float*)d_out;
  float* out0 = out;
  float* out1 = out + (size_t)16777216;   // vq_loss
  float* out2 = out + (size_t)16777217;   // indices as float [65536]

  char* ws = (char*)d_ws;
  double*   accd = (double*)(ws + 0);
  unsigned* cntA = (unsigned*)(ws + 8);
  unsigned* cntB = (unsigned*)(ws + 12);
  float*    se   = (float*)(ws + 64);        // 4 KiB
  unsigned* wlB  = (unsigned*)(ws + 4160);   // 64 KiB (16384 rows)
  uint4*    wlA  = (uint4*)(ws + 69696);     // 256 KiB (16384 entries)
  _Float16* cb16 = (_Float16*)(ws + 331840); // 512 KiB fp16 codebook (x512)

  hipMemsetAsync(d_ws, 0, 16, stream);       // zero accd + cntA + cntB
  vq_prep  <<<dim3(1024), dim3(64),  0, stream>>>(cb, se, cb16);
  vq_scores<<<dim3(1024), dim3(512), 0, stream>>>(x, cb, cb16, se, out0, out2,
                                                  wlB, wlA, cntB, cntA, accd);
  vq_pair  <<<dim3(64),   dim3(256), 0, stream>>>(x, cb, se, wlA, cntA, out2, out0, accd);
  vq_refine<<<dim3(64),   dim3(256), 0, stream>>>(x, cb, se, wlB, cntB, out2, out0, accd);
  vq_final <<<dim3(1),    dim3(1),   0, stream>>>(accd, out1);
}